// Round 2
// baseline (12858.804 us; speedup 1.0000x reference)
//
#include <hip/hip_runtime.h>
#include <hip/hip_bf16.h>
#include <math.h>

// Problem constants
#define Bb 4
#define Tt 512
#define Cc 768
#define Hh 12
#define Ll 8
#define Vv 512
#define FFf 3072
#define HDd 64

typedef __hip_bfloat16 bf16;

__device__ __forceinline__ float b2f(bf16 x){ return __bfloat162float(x); }
__device__ __forceinline__ bf16 f2b(float x){ return __float2bfloat16(x); }

// dtype-flexible input load / output store. f32!=0 -> buffers are float32,
// else bf16. Flag is wave-uniform (read from ws) -> no divergence cost.
__device__ __forceinline__ float ldin(const void* p, size_t i, int f32){
  return f32 ? ((const float*)p)[i] : b2f(((const bf16*)p)[i]);
}
__device__ __forceinline__ void stout(void* p, size_t i, float v, int f32){
  if(f32) ((float*)p)[i] = v; else ((bf16*)p)[i] = f2b(v);
}

// ---------------- dtype detect: scan tok_emb viewed as bf16 ----------------
// f32-stored data viewed as u16: mantissa halfwords have random exponent
// fields -> some |v| >= 2^17 guaranteed. Real bf16 data here is ~N(0,0.02).
__global__ __launch_bounds__(256) void detect_kernel(const void* tok, int* flag){
  __shared__ int any;
  int tid = threadIdx.x;
  if(tid==0) any = 0;
  __syncthreads();
  const unsigned short* u = (const unsigned short*)tok;
  int local = 0;
  for(int i = tid; i < 16384; i += 256){     // 32 KB: safe for both widths
    unsigned short e = (u[i] >> 7) & 0xFF;   // exponent field of bf16 view
    if(e >= 0x90) local = 1;                 // |v| >= 2^17
  }
  if(local) any = 1;
  __syncthreads();
  if(tid==0) flag[0] = any;                  // 1 => float32 I/O
}

// ---------------- embeddings: x = tok[idx] + pos + type[1] ----------------
__global__ __launch_bounds__(256) void embed_kernel(const int* __restrict__ idx,
    const void* __restrict__ tok, const void* __restrict__ typ,
    const void* __restrict__ pos, float* __restrict__ x, const int* flagp){
  int f32 = *flagp;
  int i = blockIdx.x*256 + threadIdx.x;       // over B*T*C
  int c = i % Cc;
  int bt = i / Cc;
  int t = bt % Tt;
  int row = idx[bt];
  x[i] = ldin(tok,(size_t)row*Cc+c,f32) + ldin(pos,(size_t)t*Cc+c,f32)
       + ldin(typ,(size_t)Cc+c,f32);
}

// ---------------- LayerNorm over C=768, one block per row ----------------
// w/b read at element offset po. Optionally mirrors result to out (bf16/f32).
__global__ __launch_bounds__(256) void ln_kernel(const float* __restrict__ x,
    const void* __restrict__ w, const void* __restrict__ b, size_t po,
    float* __restrict__ out, void* __restrict__ outBase, size_t off0,
    const int* flagp){
  int f32 = *flagp;
  int row = blockIdx.x, tid = threadIdx.x;
  const float* xr = x + (size_t)row*Cc;
  float v0=xr[tid], v1=xr[tid+256], v2=xr[tid+512];
  __shared__ float red[256];
  red[tid]=v0+v1+v2; __syncthreads();
  for(int off=128; off>0; off>>=1){ if(tid<off) red[tid]+=red[tid+off]; __syncthreads(); }
  float mean = red[0]*(1.0f/Cc);
  __syncthreads();
  float d0=v0-mean, d1=v1-mean, d2=v2-mean;
  red[tid]=d0*d0+d1*d1+d2*d2; __syncthreads();
  for(int off=128; off>0; off>>=1){ if(tid<off) red[tid]+=red[tid+off]; __syncthreads(); }
  float rstd = rsqrtf(red[0]*(1.0f/Cc) + 1e-5f);
  float o0 = d0*rstd*ldin(w,po+tid    ,f32) + ldin(b,po+tid    ,f32);
  float o1 = d1*rstd*ldin(w,po+tid+256,f32) + ldin(b,po+tid+256,f32);
  float o2 = d2*rstd*ldin(w,po+tid+512,f32) + ldin(b,po+tid+512,f32);
  float* orow = out + (size_t)row*Cc;
  orow[tid]=o0; orow[tid+256]=o1; orow[tid+512]=o2;
  if(outBase){
    size_t o = off0 + (size_t)row*Cc;
    stout(outBase,o+tid    ,o0,f32);
    stout(outBase,o+tid+256,o1,f32);
    stout(outBase,o+tid+512,o2,f32);
  }
}

// ---- GEMM: out[M,N] = A[M,K](f32) @ B[K,N] (+bias)(gelu)(+resid) ----
// B read at element offset bo0, bias at element offset vo0.
// BT=true: B is [N,K] row-major, used transposed (logits head).
// 64x64 tile, BK=16, 256 threads, 4x4/thread. M%64==0, N%64==0, K%16==0.
template<bool BT, bool GELU>
__global__ __launch_bounds__(256) void gemm_kernel(const float* __restrict__ A,
    const void* __restrict__ Bw, size_t bo0,
    const void* __restrict__ bias, size_t vo0,
    const float* __restrict__ resid, float* __restrict__ outF,
    void* __restrict__ outBase, size_t off0, int M, int N, int K,
    const int* flagp){
  int f32 = *flagp;
  __shared__ float As[16][65];
  __shared__ float Bs[16][65];
  int tid = threadIdx.x;
  int n0 = blockIdx.x*64, m0 = blockIdx.y*64;
  int tn = tid & 15, tm = tid >> 4;
  float acc[4][4] = {{0,0,0,0},{0,0,0,0},{0,0,0,0},{0,0,0,0}};

  int am = tid >> 2;          // 0..63
  int ak = (tid & 3) * 4;     // 0,4,8,12
  int bn = (tid & 15) * 4;
  int bk = tid >> 4;

  for(int k0 = 0; k0 < K; k0 += 16){
    float4 av = *(const float4*)(A + (size_t)(m0+am)*K + k0 + ak);
    As[ak+0][am]=av.x; As[ak+1][am]=av.y; As[ak+2][am]=av.z; As[ak+3][am]=av.w;
    if(!BT){
      size_t bo = bo0 + (size_t)(k0+bk)*N + n0 + bn;
      Bs[bk][bn+0]=ldin(Bw,bo+0,f32); Bs[bk][bn+1]=ldin(Bw,bo+1,f32);
      Bs[bk][bn+2]=ldin(Bw,bo+2,f32); Bs[bk][bn+3]=ldin(Bw,bo+3,f32);
    } else {
      size_t bo = bo0 + (size_t)(n0+am)*K + k0 + ak;
      Bs[ak+0][am]=ldin(Bw,bo+0,f32); Bs[ak+1][am]=ldin(Bw,bo+1,f32);
      Bs[ak+2][am]=ldin(Bw,bo+2,f32); Bs[ak+3][am]=ldin(Bw,bo+3,f32);
    }
    __syncthreads();
    #pragma unroll
    for(int kk=0; kk<16; kk++){
      float a[4], bb[4];
      #pragma unroll
      for(int i=0;i<4;i++) a[i]  = As[kk][tm*4+i];
      #pragma unroll
      for(int j=0;j<4;j++) bb[j] = Bs[kk][tn*4+j];
      #pragma unroll
      for(int i=0;i<4;i++)
        #pragma unroll
        for(int j=0;j<4;j++)
          acc[i][j] = fmaf(a[i], bb[j], acc[i][j]);
    }
    __syncthreads();
  }

  #pragma unroll
  for(int i=0;i<4;i++){
    int row = m0 + tm*4 + i;
    #pragma unroll
    for(int j=0;j<4;j++){
      int col = n0 + tn*4 + j;
      float v = acc[i][j];
      if(bias) v += ldin(bias,vo0+col,f32);
      if(GELU) v = 0.5f*v*(1.0f + erff(v*0.70710678118f));
      if(resid) v += resid[(size_t)row*N + col];
      if(outF) outF[(size_t)row*N + col] = v;
      if(outBase) stout(outBase, off0 + (size_t)row*N + col, v, f32);
    }
  }
}

// -------- attention scores + causal softmax, one block per (b,h,qt) row ----
__global__ __launch_bounds__(256) void attn_kernel(const float* __restrict__ q,
    const float* __restrict__ k, void* __restrict__ outBase, size_t off0,
    const int* flagp){
  int f32 = *flagp;
  int bid = blockIdx.x;            // ((b*H + h)*T + qt)
  int qt = bid % Tt;
  int h  = (bid / Tt) % Hh;
  int b  = bid / (Tt*Hh);
  int tid = threadIdx.x;
  __shared__ float sq[HDd];
  __shared__ float red[256];
  if(tid < HDd) sq[tid] = q[(size_t)(b*Tt+qt)*Cc + h*HDd + tid];
  __syncthreads();
  float s[2];
  #pragma unroll
  for(int i=0;i<2;i++){
    int kt = tid + i*256;
    if(kt <= qt){
      const float* kr = k + (size_t)(b*Tt+kt)*Cc + h*HDd;
      float acc = 0.f;
      #pragma unroll
      for(int j=0;j<HDd;j++) acc = fmaf(sq[j], kr[j], acc);
      s[i] = acc * 0.125f;   // 1/sqrt(64)
    } else s[i] = -INFINITY;
  }
  float m = fmaxf(s[0], s[1]);
  red[tid]=m; __syncthreads();
  for(int off=128; off>0; off>>=1){ if(tid<off) red[tid]=fmaxf(red[tid],red[tid+off]); __syncthreads(); }
  m = red[0];
  __syncthreads();
  float e0 = expf(s[0]-m), e1 = expf(s[1]-m);   // exp(-inf)=0 for masked
  red[tid]=e0+e1; __syncthreads();
  for(int off=128; off>0; off>>=1){ if(tid<off) red[tid]+=red[tid+off]; __syncthreads(); }
  float inv = 1.0f/red[0];
  size_t ar = off0 + (size_t)bid*Tt;
  stout(outBase, ar+tid    , e0*inv, f32);
  stout(outBase, ar+tid+256, e1*inv, f32);
}

// -------- y = att @ v, one 64-thread block per (b,h,qt) row ----------------
__global__ __launch_bounds__(64) void av_kernel(const void* __restrict__ attBase,
    size_t off0, const float* __restrict__ v, float* __restrict__ y,
    const int* flagp){
  int f32 = *flagp;
  int bid = blockIdx.x;
  int qt = bid % Tt;
  int h  = (bid / Tt) % Hh;
  int b  = bid / (Tt*Hh);
  int hd = threadIdx.x;
  size_t ar = off0 + (size_t)bid*Tt;
  float acc = 0.f;
  for(int kt=0; kt<=qt; kt++)
    acc = fmaf(ldin(attBase,ar+kt,f32), v[(size_t)(b*Tt+kt)*Cc + h*HDd + hd], acc);
  y[(size_t)(b*Tt+qt)*Cc + h*HDd + hd] = acc;
}

extern "C" void kernel_launch(void* const* d_in, const int* in_sizes, int n_in,
                              void* d_out, int out_size, void* d_ws, size_t ws_size,
                              hipStream_t stream) {
  (void)in_sizes; (void)n_in; (void)out_size; (void)ws_size;
  const int*  idx  = (const int*)d_in[0];
  const void* tok  = d_in[1];
  const void* typ  = d_in[2];
  const void* pos  = d_in[3];
  const void* Wq   = d_in[4];
  const void* bq   = d_in[5];
  const void* Wk   = d_in[6];
  const void* bk   = d_in[7];
  const void* Wv   = d_in[8];
  const void* bv   = d_in[9];
  const void* Wp   = d_in[10];
  const void* bp   = d_in[11];
  const void* ln1w = d_in[12];
  const void* ln1b = d_in[13];
  const void* ln2w = d_in[14];
  const void* ln2b = d_in[15];
  const void* W1   = d_in[16];
  const void* b1   = d_in[17];
  const void* W2   = d_in[18];
  const void* b2   = d_in[19];
  const void* lnfw = d_in[20];
  const void* lnfb = d_in[21];
  const void* headw= d_in[22];

  const size_t NTC = (size_t)Bb*Tt*Cc;        // 1,572,864
  const size_t ATT_L = (size_t)Bb*Hh*Tt*Tt;   // 12,582,912

  float* x  = (float*)d_ws;
  float* h  = x + NTC;
  float* q  = h + NTC;
  float* k  = q + NTC;
  float* v  = k + NTC;
  float* y  = v + NTC;
  float* ff = y + NTC;                        // B*T*FF floats
  int* flag = (int*)(ff + (size_t)Bb*Tt*FFf);

  const size_t offX   = (size_t)Bb*Tt*Vv;     // d_out element offsets
  const size_t offAtt = offX + NTC;

  const int M = Bb*Tt;                        // 2048
  dim3 blk(256);
  dim3 gC(Cc/64,  M/64);
  dim3 gF(FFf/64, M/64);
  dim3 gV(Vv/64,  M/64);

  detect_kernel<<<1, blk, 0, stream>>>(tok, flag);
  embed_kernel<<<(Bb*Tt*Cc)/256, blk, 0, stream>>>(idx, tok, typ, pos, x, flag);

  for(int l=0; l<Ll; l++){
    const size_t wC  = (size_t)l*Cc*Cc;
    const size_t wF1 = (size_t)l*Cc*FFf;
    const size_t wF2 = (size_t)l*FFf*Cc;
    const size_t vC  = (size_t)l*Cc;
    const size_t vF  = (size_t)l*FFf;
    const size_t attOff = offAtt + (size_t)l*ATT_L;

    ln_kernel<<<M, blk, 0, stream>>>(x, ln1w, ln1b, vC, h, nullptr, 0, flag);
    gemm_kernel<false,false><<<gC, blk, 0, stream>>>(h, Wq, wC, bq, vC, nullptr, q, nullptr, 0, M, Cc, Cc, flag);
    gemm_kernel<false,false><<<gC, blk, 0, stream>>>(h, Wk, wC, bk, vC, nullptr, k, nullptr, 0, M, Cc, Cc, flag);
    gemm_kernel<false,false><<<gC, blk, 0, stream>>>(h, Wv, wC, bv, vC, nullptr, v, nullptr, 0, M, Cc, Cc, flag);

    attn_kernel<<<Bb*Hh*Tt, blk, 0, stream>>>(q, k, d_out, attOff, flag);
    av_kernel<<<Bb*Hh*Tt, dim3(64), 0, stream>>>(d_out, attOff, v, y, flag);

    gemm_kernel<false,false><<<gC, blk, 0, stream>>>(y, Wp, wC, bp, vC, x, x, nullptr, 0, M, Cc, Cc, flag);

    ln_kernel<<<M, blk, 0, stream>>>(x, ln2w, ln2b, vC, h, nullptr, 0, flag);
    gemm_kernel<false,true ><<<gF, blk, 0, stream>>>(h, W1, wF1, b1, vF, nullptr, ff, nullptr, 0, M, FFf, Cc, flag);
    gemm_kernel<false,false><<<gC, blk, 0, stream>>>(ff, W2, wF2, b2, vC, x, x, nullptr, 0, M, Cc, FFf, flag);
  }

  ln_kernel<<<M, blk, 0, stream>>>(x, lnfw, lnfb, 0, h, d_out, offX, flag);
  gemm_kernel<true,false><<<gV, blk, 0, stream>>>(h, headw, 0, nullptr, 0, nullptr, nullptr, d_out, 0, M, Vv, Cc, flag);
}